// Round 2
// baseline (172.452 us; speedup 1.0000x reference)
//
#include <hip/hip_runtime.h>
#include <math.h>

#define NTOK 8192
#define DD   2048
#define EE   64
#define TSTRIP 16            // tokens per block (one MFMA m-tile)
#define NCH 16               // chunks per K-half (64 d each)
#define PROB_N (NTOK*2)
#define AROW 136             // 128 feats + 8 pad (halves); 272B rows, 16B aligned
// F layout: [plane:2][ck:128][nt:4][lane:64][j:8] fp16 = 1 MB
#define F_PSTRIDE (128*4*64*8)

typedef _Float16 f16x8 __attribute__((ext_vector_type(8)));
typedef _Float16 f16x4 __attribute__((ext_vector_type(4)));
typedef float    f32x4 __attribute__((ext_vector_type(4)));

// --- pinned-issue loads: volatile asm cannot be sunk/reordered by the
// compiler (R1 post-mortem: C++ prefetch loads were sunk across s_barrier,
// VGPR_Count=44 proved the double-buffer never materialized) ---
__device__ __forceinline__ f16x8 gload_f16x8(const _Float16* p) {
    f16x8 r;
    asm volatile("global_load_dwordx4 %0, %1, off" : "=v"(r) : "v"(p));
    return r;
}
__device__ __forceinline__ f32x4 gload_f32x4(const float* p) {
    f32x4 r;
    asm volatile("global_load_dwordx4 %0, %1, off" : "=v"(r) : "v"(p));
    return r;
}
// counted vmcnt wait; sched_barrier(0) stops MFMA hoisting above it (rule #18)
#define VMWAIT(n) do { \
    asm volatile("s_waitcnt vmcnt(" #n ")" ::: "memory"); \
    __builtin_amdgcn_sched_barrier(0); \
} while (0)
// LDS drain + block barrier (global loads stay in flight across it: T4)
#define LBAR() do { \
    asm volatile("s_waitcnt lgkmcnt(0)" ::: "memory"); \
    __builtin_amdgcn_s_barrier(); \
    __builtin_amdgcn_sched_barrier(0); \
} while (0)

// fast branchless atan2 (Cephes reduction + deg-7 odd minimax), ~3e-7 abs
__device__ __forceinline__ float fast_atan2f(float y, float x) {
    const float ax = __builtin_fabsf(x), ay = __builtin_fabsf(y);
    const float hi = fmaxf(ax, ay), lo = fminf(ax, ay);
    const bool  big = lo > 0.4142135679721832f * hi;       // tan(pi/8)
    const float num = big ? (lo - hi) : lo;
    const float den = big ? (lo + hi) : hi;
    float rc = __builtin_amdgcn_rcpf(den);
    rc = rc * fmaf(-den, rc, 2.0f);                        // 1 NR step
    const float z  = num * rc;
    const float z2 = z * z;
    float p = fmaf(z2, 8.05374449538e-2f, -1.38776856032e-1f);
    p = fmaf(z2, p, 1.99777106478e-1f);
    p = fmaf(z2, p, -3.33329491539e-1f);
    float r = fmaf(z * z2, p, z);
    r = r + (big ? 0.78539816339744830962f : 0.0f);
    r = (ay > ax) ? (1.57079632679489661923f - r) : r;
    r = (x < 0.0f) ? (3.14159265358979323846f - r) : r;
    return copysignf(r, y);
}

// fp16 2-split with scaled low plane: x ~= h1 + h2s*2^-11, err ~2^-24|x|
__device__ __forceinline__ void fsplit2(float x, _Float16& h1, _Float16& h2s) {
    const _Float16 a = (_Float16)x;                 // RNE, 11 bits
    h1 = a;
    h2s = (_Float16)((x - (float)a) * 2048.0f);     // next ~12 bits, normal-scaled
}

// Kernel 0: split W [4096][64] fp32 -> F fragment-order fp16 (2 planes, 1 MB)
__global__ __launch_bounds__(256) void wsplit(const float* __restrict__ W,
                                              _Float16* __restrict__ F) {
    const int g  = blockIdx.x * 256 + threadIdx.x;   // 32768 threads
    const int e  = g & 63;
    const int q  = g >> 6;          // 0..511
    const int d0 = q * 4;
    const int nt = e >> 4;
    const int lane = ((d0 & 31) >> 3) * 16 + (e & 15);
    const int j0 = d0 & 7;          // 0 or 4
    const int cka = 2 * (d0 >> 5);  // amp kstep; phase kstep = cka+1

    f16x4 a1, a2, p1, p2;
    #pragma unroll
    for (int i = 0; i < 4; ++i) {
        _Float16 h, l;
        fsplit2(W[(size_t)(d0 + i) * EE + e], h, l);      a1[i] = h; a2[i] = l;
        fsplit2(W[(size_t)(DD + d0 + i) * EE + e], h, l); p1[i] = h; p2[i] = l;
    }
    *(f16x4*)&F[((size_t)(0 * 128 + cka)     * 4 + nt) * 512 + lane * 8 + j0] = a1;
    *(f16x4*)&F[((size_t)(1 * 128 + cka)     * 4 + nt) * 512 + lane * 8 + j0] = a2;
    *(f16x4*)&F[((size_t)(0 * 128 + cka + 1) * 4 + nt) * 512 + lane * 8 + j0] = p1;
    *(f16x4*)&F[((size_t)(1 * 128 + cka + 1) * 4 + nt) * 512 + lane * 8 + j0] = p2;
}

// Kernel 1: fully fused. Block = 16 tokens, full K. 8 waves = 4 expert-tiles
// x 2 K-halves. Double-buffered LDS A; HAND-PIPELINED B/x prefetch via
// volatile-asm loads + counted vmcnt (2-chunk-deep B, 1-chunk x; 18 loads
// in flight; vmcnt never drains to 0 in the main loop).
__global__ __launch_bounds__(512, 4) void gemm_topk(
    const float* __restrict__ xr, const float* __restrict__ xi,
    const _Float16* __restrict__ F, const float* __restrict__ bias,
    float* __restrict__ out)
{
    __shared__ __align__(16) _Float16 A[2][2][2][TSTRIP][AROW];  // 34 KB
    __shared__ float scoreH[2][TSTRIP][EE];                       // 8 KB

    const int tid = threadIdx.x;
    const int t0  = blockIdx.x * TSTRIP;
    // compute roles
    const int wv = tid >> 6, lane = tid & 63;
    const int nt = wv & 3, kh = wv >> 2;
    const int fm = lane & 15, fq = lane >> 4;
    // staging roles
    const int kh_s  = tid >> 8;
    const int tok_s = (tid >> 4) & 15;
    const int f4    = tid & 15;

    const float bv = bias[lane];

    const float* prx = xr + (size_t)(t0 + tok_s) * DD + kh_s * 1024 + f4 * 4;
    const float* pix = xi + (size_t)(t0 + tok_s) * DD + kh_s * 1024 + f4 * 4;
    const int posa = 64 * (f4 >> 3) + (f4 & 7) * 4;   // amp slot; phase = +32

    auto sprocess = [&](f32x4 vr, f32x4 vi, int buf) {
        f16x4 a1, a2, p1, p2;
        #pragma unroll
        for (int i = 0; i < 4; ++i) {
            const float amp = __builtin_amdgcn_sqrtf(fmaf(vr[i], vr[i], vi[i] * vi[i]));
            const float ph  = fast_atan2f(vi[i], vr[i]);
            _Float16 h, l;
            fsplit2(amp, h, l); a1[i] = h; a2[i] = l;
            fsplit2(ph,  h, l); p1[i] = h; p2[i] = l;
        }
        *(f16x4*)&A[buf][kh_s][0][tok_s][posa]      = a1;
        *(f16x4*)&A[buf][kh_s][1][tok_s][posa]      = a2;
        *(f16x4*)&A[buf][kh_s][0][tok_s][posa + 32] = p1;
        *(f16x4*)&A[buf][kh_s][1][tok_s][posa + 32] = p2;
    };

    f32x4 accH = (f32x4){0.f, 0.f, 0.f, 0.f};
    f32x4 accL = (f32x4){0.f, 0.f, 0.f, 0.f};

    // per-wave B base: chunk c lives at bbase + c*8192 elements
    const _Float16* bbase = F + ((size_t)(kh * 64) * 4 + nt) * 512 + lane * 8;

    // register pipeline state; all indices compile-time static via full unroll
    f16x8 bh[2][4], bl[2][4];
    f32x4 xrb[2], xib[2];

    // ---- prologue ----
    // issue x(0) then B(0): outstanding = 10
    xrb[0] = gload_f32x4(prx);
    xib[0] = gload_f32x4(pix);
    #pragma unroll
    for (int j = 0; j < 4; ++j) {
        bh[0][j] = gload_f16x8(bbase + j * 2048);
        bl[0][j] = gload_f16x8(bbase + F_PSTRIDE + j * 2048);
    }
    VMWAIT(8);                       // x(0) ready; B(0) stays in flight
    sprocess(xrb[0], xib[0], 0);
    // issue x(1) then B(1): outstanding = 8 + 2 + 8 = 18
    xrb[1] = gload_f32x4(prx + 64);
    xib[1] = gload_f32x4(pix + 64);
    #pragma unroll
    for (int j = 0; j < 4; ++j) {
        bh[1][j] = gload_f16x8(bbase + 8192 + j * 2048);
        bl[1][j] = gload_f16x8(bbase + 8192 + F_PSTRIDE + j * 2048);
    }
    LBAR();

    // ---- main loop: steady-state outstanding at top = B(c)8 + x(c+1)2 + B(c+1)8
    #pragma unroll
    for (int c = 0; c < NCH; ++c) {
        const int buf = c & 1;
        if (c < NCH - 1) { VMWAIT(10); } else { VMWAIT(0); }   // B(c) ready
        #pragma unroll
        for (int j = 0; j < 4; ++j) {
            const f16x8 a1 = *(const f16x8*)&A[buf][kh][0][fm][j * 32 + fq * 8];
            const f16x8 a2 = *(const f16x8*)&A[buf][kh][1][fm][j * 32 + fq * 8];
            accH = __builtin_amdgcn_mfma_f32_16x16x32_f16(a1, bh[buf][j], accH, 0, 0, 0);
            accL = __builtin_amdgcn_mfma_f32_16x16x32_f16(a1, bl[buf][j], accL, 0, 0, 0);
            accL = __builtin_amdgcn_mfma_f32_16x16x32_f16(a2, bh[buf][j], accL, 0, 0, 0);
        }
        if (c < NCH - 1) {
            VMWAIT(8);               // x(c+1) ready; B(c+1) stays in flight
            sprocess(xrb[buf ^ 1], xib[buf ^ 1], buf ^ 1);
            if (c < NCH - 2) {
                // issue x(c+2) then B(c+2) into the slot just freed by MFMA(c)
                xrb[buf] = gload_f32x4(prx + (c + 2) * 64);
                xib[buf] = gload_f32x4(pix + (c + 2) * 64);
                const _Float16* nb = bbase + (size_t)(c + 2) * 8192;
                #pragma unroll
                for (int j = 0; j < 4; ++j) {
                    bh[buf][j] = gload_f16x8(nb + j * 2048);
                    bl[buf][j] = gload_f16x8(nb + F_PSTRIDE + j * 2048);
                }
            }
            LBAR();
        }
    }

    // D layout: col(expert-in-tile)=lane&15, row(token)=(lane>>4)*4+reg [m89]
    #pragma unroll
    for (int r = 0; r < 4; ++r)
        scoreH[kh][fq * 4 + r][nt * 16 + fm] = fmaf(accL[r], 4.8828125e-4f, accH[r]);
    __syncthreads();

    // exact top-2 (tie-break lower index, matching lax.top_k); 2 tokens/wave
    #pragma unroll
    for (int rep = 0; rep < 2; ++rep) {
        const int tok = wv * 2 + rep;
        float v1 = scoreH[0][tok][lane] + scoreH[1][tok][lane] + bv;
        float v2 = -INFINITY;
        int   i1 = lane, i2 = 64;
        #pragma unroll
        for (int off = 1; off < 64; off <<= 1) {
            const float ov1 = __shfl_xor(v1, off, 64);
            const int   oi1 = __shfl_xor(i1, off, 64);
            const float ov2 = __shfl_xor(v2, off, 64);
            const int   oi2 = __shfl_xor(i2, off, 64);
            const bool b1 = (ov1 > v1) || (ov1 == v1 && oi1 < i1);
            const float n1 = b1 ? ov1 : v1;  const int ni1 = b1 ? oi1 : i1;
            const float c1 = b1 ? v1  : ov1; const int ci1 = b1 ? i1  : oi1;
            const float c2 = b1 ? ov2 : v2;  const int ci2 = b1 ? oi2 : i2;
            const bool b2 = (c1 > c2) || (c1 == c2 && ci1 < ci2);
            v1 = n1; i1 = ni1;
            v2 = b2 ? c1 : c2; i2 = b2 ? ci1 : ci2;
        }
        if (lane == 0) {
            const int t = t0 + tok;
            const float z  = expf(v2 - v1);
            const float p1 = 1.0f / (1.0f + z);
            const float p2 = z / (1.0f + z);
            out[(size_t)t * 2 + 0] = p1;
            out[(size_t)t * 2 + 1] = p2;
            out[PROB_N + (size_t)t * 2 + 0] = (float)i1;
            out[PROB_N + (size_t)t * 2 + 1] = (float)i2;
        }
    }
}

extern "C" void kernel_launch(void* const* d_in, const int* in_sizes, int n_in,
                              void* d_out, int out_size, void* d_ws, size_t ws_size,
                              hipStream_t stream) {
    const float* xr = (const float*)d_in[0];
    const float* xi = (const float*)d_in[1];
    const float* W  = (const float*)d_in[2];
    const float* b  = (const float*)d_in[3];
    float* out = (float*)d_out;
    _Float16* F = (_Float16*)d_ws;   // 1 MB swizzled 2-plane fp16 W

    wsplit<<<128, 256, 0, stream>>>(W, F);
    gemm_topk<<<NTOK / TSTRIP, 512, 0, stream>>>(xr, xi, F, b, out);
}

// Round 3
// 170.113 us; speedup vs baseline: 1.0138x; 1.0138x over previous
//
#include <hip/hip_runtime.h>
#include <math.h>

#define NTOK 8192
#define DD   2048
#define EE   64
#define TSTRIP 32            // tokens per block (two MFMA m-tiles)
#define NCH 16               // chunks per K-half (64 d each)
#define NSLOT 3              // LDS ring depth (chunks)
#define PROB_N (NTOK*2)
#define AROW 136             // 128 feats + 8 pad; 272B rows, 16B aligned
// F layout: [plane:2][ck:128][nt:4][lane:64][j:8] fp16 = 1 MB
#define F_PSTRIDE (128*4*64*8)

typedef _Float16 f16x8 __attribute__((ext_vector_type(8)));
typedef _Float16 f16x4 __attribute__((ext_vector_type(4)));
typedef float    f32x4 __attribute__((ext_vector_type(4)));

// pinned-issue loads (R1 lesson: C++ prefetches get sunk across barriers)
__device__ __forceinline__ f16x8 gload_f16x8(const _Float16* p) {
    f16x8 r;
    asm volatile("global_load_dwordx4 %0, %1, off" : "=v"(r) : "v"(p));
    return r;
}
__device__ __forceinline__ f32x4 gload_f32x4(const float* p) {
    f32x4 r;
    asm volatile("global_load_dwordx4 %0, %1, off" : "=v"(r) : "v"(p));
    return r;
}
#define VMWAIT(n) do { \
    asm volatile("s_waitcnt vmcnt(" #n ")" ::: "memory"); \
    __builtin_amdgcn_sched_barrier(0); \
} while (0)
#define LBAR() do { \
    asm volatile("s_waitcnt lgkmcnt(0)" ::: "memory"); \
    __builtin_amdgcn_s_barrier(); \
    __builtin_amdgcn_sched_barrier(0); \
} while (0)

// fast branchless atan2 (Cephes reduction + deg-7 odd minimax), ~3e-7 abs
__device__ __forceinline__ float fast_atan2f(float y, float x) {
    const float ax = __builtin_fabsf(x), ay = __builtin_fabsf(y);
    const float hi = fmaxf(ax, ay), lo = fminf(ax, ay);
    const bool  big = lo > 0.4142135679721832f * hi;       // tan(pi/8)
    const float num = big ? (lo - hi) : lo;
    const float den = big ? (lo + hi) : hi;
    float rc = __builtin_amdgcn_rcpf(den);
    rc = rc * fmaf(-den, rc, 2.0f);                        // 1 NR step
    const float z  = num * rc;
    const float z2 = z * z;
    float p = fmaf(z2, 8.05374449538e-2f, -1.38776856032e-1f);
    p = fmaf(z2, p, 1.99777106478e-1f);
    p = fmaf(z2, p, -3.33329491539e-1f);
    float r = fmaf(z * z2, p, z);
    r = r + (big ? 0.78539816339744830962f : 0.0f);
    r = (ay > ax) ? (1.57079632679489661923f - r) : r;
    r = (x < 0.0f) ? (3.14159265358979323846f - r) : r;
    return copysignf(r, y);
}

// fp16 2-split with scaled low plane: x ~= h1 + h2s*2^-11, err ~2^-24|x|
__device__ __forceinline__ void fsplit2(float x, _Float16& h1, _Float16& h2s) {
    const _Float16 a = (_Float16)x;                 // RNE, 11 bits
    h1 = a;
    h2s = (_Float16)((x - (float)a) * 2048.0f);     // next ~12 bits, normal-scaled
}

// Kernel 0: split W [4096][64] fp32 -> F fragment-order fp16 (2 planes, 1 MB)
__global__ __launch_bounds__(256) void wsplit(const float* __restrict__ W,
                                              _Float16* __restrict__ F) {
    const int g  = blockIdx.x * 256 + threadIdx.x;   // 32768 threads
    const int e  = g & 63;
    const int q  = g >> 6;          // 0..511
    const int d0 = q * 4;
    const int nt = e >> 4;
    const int lane = ((d0 & 31) >> 3) * 16 + (e & 15);
    const int j0 = d0 & 7;          // 0 or 4
    const int cka = 2 * (d0 >> 5);  // amp kstep; phase kstep = cka+1

    f16x4 a1, a2, p1, p2;
    #pragma unroll
    for (int i = 0; i < 4; ++i) {
        _Float16 h, l;
        fsplit2(W[(size_t)(d0 + i) * EE + e], h, l);      a1[i] = h; a2[i] = l;
        fsplit2(W[(size_t)(DD + d0 + i) * EE + e], h, l); p1[i] = h; p2[i] = l;
    }
    *(f16x4*)&F[((size_t)(0 * 128 + cka)     * 4 + nt) * 512 + lane * 8 + j0] = a1;
    *(f16x4*)&F[((size_t)(1 * 128 + cka)     * 4 + nt) * 512 + lane * 8 + j0] = a2;
    *(f16x4*)&F[((size_t)(0 * 128 + cka + 1) * 4 + nt) * 512 + lane * 8 + j0] = p1;
    *(f16x4*)&F[((size_t)(1 * 128 + cka + 1) * 4 + nt) * 512 + lane * 8 + j0] = p2;
}

// Kernel 1: producer/consumer wave-specialized, NO barrier in main loop.
// 12 waves: 0-7 consumers (nt x kh, two m-tiles each), 8-11 producers
// (all sqrt/atan2/fsplit VALU). 3-slot LDS ring, LDS flag counters.
__global__ __launch_bounds__(768, 3) void gemm_topk(
    const float* __restrict__ xr, const float* __restrict__ xi,
    const _Float16* __restrict__ F, const float* __restrict__ bias,
    float* __restrict__ out)
{
    __shared__ __align__(16) _Float16 A[NSLOT][2][2][TSTRIP][AROW];  // 102 KB
    __shared__ float scoreH[2][TSTRIP][EE];                           // 16 KB
    __shared__ int rdy[NCH];   // producer-wave signals per chunk (target 4)
    __shared__ int dne[NCH];   // consumer-wave signals per chunk (target 8)

    const int tid = threadIdx.x;
    const int t0  = blockIdx.x * TSTRIP;
    const int wv = tid >> 6, lane = tid & 63;

    if (tid < NCH) { rdy[tid] = 0; dne[tid] = 0; }

    if (wv < 8) {
        // ---------------- consumers ----------------
        const int nt = wv & 3, kh = wv >> 2;
        const int fm = lane & 15, fq = lane >> 4;
        const _Float16* bbase = F + ((size_t)(kh * 64) * 4 + nt) * 512 + lane * 8;

        f16x8 bh[2][4], bl[2][4];
        #pragma unroll
        for (int j = 0; j < 4; ++j) {
            bh[0][j] = gload_f16x8(bbase + j * 2048);
            bl[0][j] = gload_f16x8(bbase + F_PSTRIDE + j * 2048);
        }
        LBAR();                       // init barrier (flags zeroed)

        f32x4 accH0 = (f32x4){0.f,0.f,0.f,0.f}, accL0 = (f32x4){0.f,0.f,0.f,0.f};
        f32x4 accH1 = (f32x4){0.f,0.f,0.f,0.f}, accL1 = (f32x4){0.f,0.f,0.f,0.f};

        #pragma unroll
        for (int c = 0; c < NCH; ++c) {
            const int buf = c & 1;
            if (c < NCH - 1) {        // issue B(c+1); flies during poll
                const _Float16* nb = bbase + (size_t)(c + 1) * 8192;
                #pragma unroll
                for (int j = 0; j < 4; ++j) {
                    bh[buf ^ 1][j] = gload_f16x8(nb + j * 2048);
                    bl[buf ^ 1][j] = gload_f16x8(nb + F_PSTRIDE + j * 2048);
                }
            }
            while (*(volatile int*)&rdy[c] < 4) __builtin_amdgcn_s_sleep(1);
            __builtin_amdgcn_sched_barrier(0);
            if (c < NCH - 1) { VMWAIT(8); } else { VMWAIT(0); }   // B(c) ready
            #pragma unroll
            for (int j = 0; j < 4; ++j) {
                const int co = j * 32 + fq * 8;
                const f16x8 a10 = *(const f16x8*)&A[c % NSLOT][kh][0][fm][co];
                const f16x8 a20 = *(const f16x8*)&A[c % NSLOT][kh][1][fm][co];
                const f16x8 a11 = *(const f16x8*)&A[c % NSLOT][kh][0][fm + 16][co];
                const f16x8 a21 = *(const f16x8*)&A[c % NSLOT][kh][1][fm + 16][co];
                accH0 = __builtin_amdgcn_mfma_f32_16x16x32_f16(a10, bh[buf][j], accH0, 0, 0, 0);
                accL0 = __builtin_amdgcn_mfma_f32_16x16x32_f16(a10, bl[buf][j], accL0, 0, 0, 0);
                accL0 = __builtin_amdgcn_mfma_f32_16x16x32_f16(a20, bh[buf][j], accL0, 0, 0, 0);
                accH1 = __builtin_amdgcn_mfma_f32_16x16x32_f16(a11, bh[buf][j], accH1, 0, 0, 0);
                accL1 = __builtin_amdgcn_mfma_f32_16x16x32_f16(a11, bl[buf][j], accL1, 0, 0, 0);
                accL1 = __builtin_amdgcn_mfma_f32_16x16x32_f16(a21, bh[buf][j], accL1, 0, 0, 0);
            }
            asm volatile("s_waitcnt lgkmcnt(0)" ::: "memory");   // a-reads retired
            if (lane == 0) atomicAdd(&dne[c], 1);
        }
        // D layout: col=lane&15, row=(lane>>4)*4+reg [m89]
        #pragma unroll
        for (int r = 0; r < 4; ++r) {
            scoreH[kh][fq * 4 + r][nt * 16 + fm]      = fmaf(accL0[r], 4.8828125e-4f, accH0[r]);
            scoreH[kh][16 + fq * 4 + r][nt * 16 + fm] = fmaf(accL1[r], 4.8828125e-4f, accH1[r]);
        }
    } else {
        // ---------------- producers ----------------
        const int ptid = tid - 512;               // 0..255
        const int f8   = ptid & 7;                // 8-feat group within 64-chunk
        const int tokp = ptid >> 3;               // 0..31
        const float* prx = xr + (size_t)(t0 + tokp) * DD + f8 * 8;
        const float* pix = xi + (size_t)(t0 + tokp) * DD + f8 * 8;
        const int wpos = (f8 >> 2) * 64 + (f8 & 3) * 8;   // amp pos; phase +32

        f32x4 R0[4], I0[4], R1[4], I1[4];         // [kh*2+h], const-indexed only

        auto pload = [&](int c, f32x4* R, f32x4* I) {
            #pragma unroll
            for (int k2 = 0; k2 < 2; ++k2)
                #pragma unroll
                for (int h = 0; h < 2; ++h) {
                    R[k2 * 2 + h] = gload_f32x4(prx + k2 * 1024 + c * 64 + h * 4);
                    I[k2 * 2 + h] = gload_f32x4(pix + k2 * 1024 + c * 64 + h * 4);
                }
        };
        auto pstore = [&](int c, f32x4* R, f32x4* I) {
            const int slot = c % NSLOT;
            #pragma unroll
            for (int k2 = 0; k2 < 2; ++k2) {
                f16x8 a1, a2, p1, p2;
                #pragma unroll
                for (int h = 0; h < 2; ++h)
                    #pragma unroll
                    for (int i = 0; i < 4; ++i) {
                        const float rr = R[k2 * 2 + h][i], im = I[k2 * 2 + h][i];
                        const float amp = __builtin_amdgcn_sqrtf(fmaf(rr, rr, im * im));
                        const float ph  = fast_atan2f(im, rr);
                        _Float16 hh, ll;
                        fsplit2(amp, hh, ll); a1[h * 4 + i] = hh; a2[h * 4 + i] = ll;
                        fsplit2(ph,  hh, ll); p1[h * 4 + i] = hh; p2[h * 4 + i] = ll;
                    }
                *(f16x8*)&A[slot][k2][0][tokp][wpos]      = a1;
                *(f16x8*)&A[slot][k2][1][tokp][wpos]      = a2;
                *(f16x8*)&A[slot][k2][0][tokp][wpos + 32] = p1;
                *(f16x8*)&A[slot][k2][1][tokp][wpos + 32] = p2;
            }
        };

        pload(0, R0, I0);                         // 8 outstanding
        pload(1, R1, I1);                         // 16 outstanding
        LBAR();                                   // init barrier

        #define PBODY(c, R, I, DO_ISSUE, WN) do { \
            if ((c) >= 3) { while (*(volatile int*)&dne[(c) - 3] < 8) __builtin_amdgcn_s_sleep(1); } \
            __builtin_amdgcn_sched_barrier(0); \
            VMWAIT(WN); \
            pstore((c), R, I); \
            asm volatile("s_waitcnt lgkmcnt(0)" ::: "memory"); \
            if (lane == 0) atomicAdd(&rdy[(c)], 1); \
            if (DO_ISSUE) pload((c) + 2, R, I); \
        } while (0)

        for (int cc = 0; cc < 7; ++cc) {          // c = 0..13, paired parities
            const int c0 = 2 * cc, c1 = 2 * cc + 1;
            PBODY(c0, R0, I0, 1, 8);
            PBODY(c1, R1, I1, 1, 8);
        }
        PBODY(14, R0, I0, 0, 8);
        PBODY(15, R1, I1, 0, 0);
        #undef PBODY
    }

    LBAR();                                       // final barrier (all 12 waves)

    if (wv < 8) {
        // exact top-2 (tie-break lower index); 4 tokens per consumer wave
        const float bv = bias[lane];
        #pragma unroll
        for (int rep = 0; rep < 4; ++rep) {
            const int tok = wv * 4 + rep;
            float v1 = scoreH[0][tok][lane] + scoreH[1][tok][lane] + bv;
            float v2 = -INFINITY;
            int   i1 = lane, i2 = 64;
            #pragma unroll
            for (int off = 1; off < 64; off <<= 1) {
                const float ov1 = __shfl_xor(v1, off, 64);
                const int   oi1 = __shfl_xor(i1, off, 64);
                const float ov2 = __shfl_xor(v2, off, 64);
                const int   oi2 = __shfl_xor(i2, off, 64);
                const bool b1 = (ov1 > v1) || (ov1 == v1 && oi1 < i1);
                const float n1 = b1 ? ov1 : v1;  const int ni1 = b1 ? oi1 : i1;
                const float c1 = b1 ? v1  : ov1; const int ci1 = b1 ? i1  : oi1;
                const float c2 = b1 ? ov2 : v2;  const int ci2 = b1 ? oi2 : i2;
                const bool b2 = (c1 > c2) || (c1 == c2 && ci1 < ci2);
                v1 = n1; i1 = ni1;
                v2 = b2 ? c1 : c2; i2 = b2 ? ci1 : ci2;
            }
            if (lane == 0) {
                const int t = t0 + tok;
                const float z  = expf(v2 - v1);
                const float p1 = 1.0f / (1.0f + z);
                const float p2 = z / (1.0f + z);
                out[(size_t)t * 2 + 0] = p1;
                out[(size_t)t * 2 + 1] = p2;
                out[PROB_N + (size_t)t * 2 + 0] = (float)i1;
                out[PROB_N + (size_t)t * 2 + 1] = (float)i2;
            }
        }
    }
}

extern "C" void kernel_launch(void* const* d_in, const int* in_sizes, int n_in,
                              void* d_out, int out_size, void* d_ws, size_t ws_size,
                              hipStream_t stream) {
    const float* xr = (const float*)d_in[0];
    const float* xi = (const float*)d_in[1];
    const float* W  = (const float*)d_in[2];
    const float* b  = (const float*)d_in[3];
    float* out = (float*)d_out;
    _Float16* F = (_Float16*)d_ws;   // 1 MB swizzled 2-plane fp16 W

    wsplit<<<128, 256, 0, stream>>>(W, F);
    gemm_topk<<<NTOK / TSTRIP, 768, 0, stream>>>(xr, xi, F, b, out);
}